// Round 8
// baseline (144.031 us; speedup 1.0000x reference)
//
#include <hip/hip_runtime.h>
#include <hip/hip_bf16.h>
#include <stdint.h>

// Problem constants
#define B_  2
#define S_  2048
#define D_  1024
#define H_  16
#define DQ_ 64
#define QT_ (S_/64)   // 32 q-tiles (64 rows each) per (b,h)

// softmax is shift-invariant -> no max subtraction needed at all.
// scale folded into Q pack: qb = bf16(q * 0.125 * log2(e)), P = exp2(K·qb)
#define C1_ 0.18033688011112042f   // 0.125 * log2(e)

typedef float f32x4  __attribute__((ext_vector_type(4)));
typedef float f32x16 __attribute__((ext_vector_type(16)));
typedef short bf16x8 __attribute__((ext_vector_type(8)));

__device__ __forceinline__ unsigned short f2bf(float f) {
    uint32_t u = __float_as_uint(f);
    u += 0x7fffu + ((u >> 16) & 1u);   // round-to-nearest-even
    return (unsigned short)(u >> 16);
}
__device__ __forceinline__ float bf2f(unsigned short u) {
    return __uint_as_float(((uint32_t)u) << 16);
}
__device__ __forceinline__ float fast_exp2(float x) {
#if __has_builtin(__builtin_amdgcn_exp2f)
    return __builtin_amdgcn_exp2f(x);
#else
    float r; asm("v_exp_f32 %0, %1" : "=v"(r) : "v"(x)); return r;
#endif
}
__device__ __forceinline__ uint32_t cvt_pk_bf16(float lo, float hi) {
    uint32_t r;
    asm("v_cvt_pk_bf16_f32 %0, %1, %2" : "=v"(r) : "v"(lo), "v"(hi));
    return r;
}
// vdst[32..63] <-> vsrc[0..31]
__device__ __forceinline__ void permlane32_swap(uint32_t &a, uint32_t &b) {
    asm volatile("v_permlane32_swap_b32 %0, %1" : "+v"(a), "+v"(b));
}

// ---------------------------------------------------------------------------
// Kernel 1: prep. Emits K and V in EXACT 32x32x16-MFMA fragment order via an
// LDS-staged tile transpose so BOTH the global loads (row-segmented float4,
// 16 cache lines / wave-instr) and the fragment stores (consecutive tid ->
// consecutive 16B) are fully coalesced. Also Wo fp32->bf16 and Pv column
// partials (row-0 mean(V)). Grid 3072 x 256:
//   [0,1024)    : Vf fragments + Pv   (g = blk>>5, j = blk&31)
//   [1024,2048) : Kf fragments
//   [2048,3072) : Wo convert
// Kf frag fb = wk*4+s : lane l holds K[j*64+wk*32+(l&31)][s*16+(l>>5)*8 + 0..7]
// Vf frag fb = s*2+kk : lane l holds V[j*64+s*16+(l>>5)*8 + 0..7][kk*32+(l&31)]
// ---------------------------------------------------------------------------
__global__ __launch_bounds__(256) void prep_kernel(
    const float* __restrict__ K, const float* __restrict__ V,
    const float* __restrict__ W,
    unsigned short* __restrict__ Kf, unsigned short* __restrict__ Vf,
    unsigned short* __restrict__ Wb, float* __restrict__ Pv)
{
    __shared__ unsigned short Ls[64][72];
    __shared__ float Pp[8][64];
    const int blk = blockIdx.x, tid = threadIdx.x;

    if (blk < 2048) {
        const bool isV = blk < 1024;
        const int gb = isV ? blk : (blk - 1024);
        const int g = gb >> 5, j = gb & 31;
        const int b = g >> 4, h = g & 15;
        const float* src0 = (isV ? V : K) + ((size_t)(b*S_ + j*64))*D_ + h*64;

        // phase A: coalesced tile load (64 rows x 64 cols fp32) -> bf16 LDS
        {
            int row = tid >> 2, col0 = (tid & 3) * 16;
            const float* src = src0 + (size_t)row*D_ + col0;
            float4 f0 = ((const float4*)src)[0];
            float4 f1 = ((const float4*)src)[1];
            float4 f2 = ((const float4*)src)[2];
            float4 f3 = ((const float4*)src)[3];
            unsigned short* d = &Ls[row][col0];
            d[0]=f2bf(f0.x); d[1]=f2bf(f0.y); d[2]=f2bf(f0.z); d[3]=f2bf(f0.w);
            d[4]=f2bf(f1.x); d[5]=f2bf(f1.y); d[6]=f2bf(f1.z); d[7]=f2bf(f1.w);
            d[8]=f2bf(f2.x); d[9]=f2bf(f2.y); d[10]=f2bf(f2.z); d[11]=f2bf(f2.w);
            d[12]=f2bf(f3.x); d[13]=f2bf(f3.y); d[14]=f2bf(f3.z); d[15]=f2bf(f3.w);
        }
        __syncthreads();

        if (isV) {
            // phase B: transpose via LDS scalar reads -> coalesced frag stores
            #pragma unroll
            for (int ps = 0; ps < 2; ++ps) {
                const int slot = tid + ps*256;
                const int fb = slot >> 6, l = slot & 63;
                const int s = fb >> 1, kk = fb & 1;
                const int hi = l >> 5, l31 = l & 31;
                const int dcol = kk*32 + l31;
                unsigned short us[8];
                float p = 0.f;
                #pragma unroll
                for (int r = 0; r < 8; ++r) {
                    unsigned short u = Ls[s*16 + hi*8 + r][dcol];
                    us[r] = u;
                    p += bf2f(u);
                }
                *(uint4*)(Vf + ((size_t)gb*8 + fb)*512 + (size_t)l*8) = *(uint4*)us;
                Pp[s*2 + hi][dcol] = p;
            }
            __syncthreads();
            if (tid < 64) {
                float t = 0.f;
                #pragma unroll
                for (int i = 0; i < 8; ++i) t += Pp[i][tid];
                Pv[((size_t)g*64 + tid)*32 + j] = t;
            }
        } else {
            // phase B: rows are fragment-contiguous -> b128 LDS reads
            #pragma unroll
            for (int ps = 0; ps < 2; ++ps) {
                const int slot = tid + ps*256;
                const int fb = slot >> 6, l = slot & 63;
                const int wk = fb >> 2, s = fb & 3;
                const int hi = l >> 5, l31 = l & 31;
                uint4 val = *(const uint4*)&Ls[wk*32 + l31][s*16 + hi*8];
                *(uint4*)(Kf + ((size_t)gb*8 + fb)*512 + (size_t)l*8) = val;
            }
        }
    } else {
        int i = (blk - 2048)*256 + tid;     // < D*D/4 = 262144
        float4 f = ((const float4*)W)[i];
        ushort4 o;
        o.x = f2bf(f.x); o.y = f2bf(f.y); o.z = f2bf(f.z); o.w = f2bf(f.w);
        ((ushort4*)Wb)[i] = o;
    }
}

// ---------------------------------------------------------------------------
// Kernel 2: flash attention, 32x32x16 MFMA, zero-LDS main loop.
// R8 changes (R7 residency math: waves stall ~2200cy/iter on serial chains):
//  - QK^T split into TWO parallel 2-deep MFMA chains (st0,st1 + vector add):
//    serial ~200 -> ~110 cy.
//  - PV split into FOUR independent accumulators (o00,o01,o10,o11; summed
//    once in the epilogue): per-iter PV chain 2 -> 1 MFMA, cross-iteration
//    chain 2 -> 1 MFMA per accumulator.
//  - LONGEST-FIRST dispatch: p -> qt = {31-p, p+8, 31-p, p-24} per octile.
//    Per-CU quadruples {p,p+8,p+16,p+24} still sum to 62 (balanced), but
//    qt=31..24 blocks launch first -> no long-block tail at drain time.
// Retained: depth-2 ping-pong prefetch (ka/va,kb/vb), Q staged via LDS,
// setprio around MFMA clusters, shift-free softmax, per-wave causal niter,
// bid&7 = g&7 XCD affinity, single end barrier.
// launch_bounds (256,2): do NOT raise the 2nd arg (R4/R5: allocator spill).
// ---------------------------------------------------------------------------
__global__ __launch_bounds__(256, 2) void attn_kernel(
    const float* __restrict__ Q,
    const unsigned short* __restrict__ Kf,
    const unsigned short* __restrict__ Vf,
    const float* __restrict__ Pv,
    unsigned short* __restrict__ ctx,
    const int* __restrict__ maskp)
{
    __shared__ union {
        unsigned short qs[64][72];                    // Q staging (prologue)
        struct { float osum[2][32][68]; float lsum[2][32]; } red;  // epilogue
    } sm;

    const int bid = blockIdx.x;
    const int g = bid & 31;             // h + 16*b ; g&7 = bid&7 -> XCD
    const int p = bid >> 5;             // [0,32)
    // longest-first balanced permutation: octiles -> qt {31..24,16..23,15..8,0..7}
    const int qt = (p < 8) ? 31 - p : (p < 16) ? p + 8 : (p < 24) ? 31 - p : p - 24;
    const int h = g & 15, b = g >> 4;
    const int tid  = threadIdx.x;
    const int wave = tid >> 6, lane = tid & 63;
    const int wq = wave >> 1, wk = wave & 1;
    const int hi = lane >> 5, l31 = lane & 31;
    const int maskv = maskp[0];

    // fused mean(V) -> ctx row 0, cols [h*64, h*64+64)
    if (maskv && qt == 0 && tid < 64) {
        const float* pv = Pv + ((size_t)g*64 + tid)*32;
        float s = 0.f;
        #pragma unroll
        for (int i = 0; i < 32; ++i) s += pv[i];
        ctx[(size_t)b*S_*D_ + h*64 + tid] = f2bf(s * (1.0f/S_));
    }

    // ---- stage Q tile (coalesced) -> LDS as pre-scaled bf16 ----
    {
        const int row = tid >> 2, col0 = (tid & 3) * 16;
        const float* src = Q + ((size_t)(b*S_ + qt*64 + row))*D_ + h*64 + col0;
        float4 f0 = ((const float4*)src)[0];
        float4 f1 = ((const float4*)src)[1];
        float4 f2 = ((const float4*)src)[2];
        float4 f3 = ((const float4*)src)[3];
        unsigned short* d = &sm.qs[row][col0];
        d[0]=f2bf(f0.x*C1_); d[1]=f2bf(f0.y*C1_); d[2]=f2bf(f0.z*C1_); d[3]=f2bf(f0.w*C1_);
        d[4]=f2bf(f1.x*C1_); d[5]=f2bf(f1.y*C1_); d[6]=f2bf(f1.z*C1_); d[7]=f2bf(f1.w*C1_);
        d[8]=f2bf(f2.x*C1_); d[9]=f2bf(f2.y*C1_); d[10]=f2bf(f2.z*C1_); d[11]=f2bf(f2.w*C1_);
        d[12]=f2bf(f3.x*C1_); d[13]=f2bf(f3.y*C1_); d[14]=f2bf(f3.z*C1_); d[15]=f2bf(f3.w*C1_);
    }
    __syncthreads();
    bf16x8 qf[4];
    #pragma unroll
    for (int s = 0; s < 4; ++s)
        qf[s] = *(const bf16x8*)&sm.qs[wq*32 + l31][s*16 + hi*8];
    __syncthreads();   // Qs reads done before epilogue aliases the buffer

    // fragment bases (advance by j*4096 ushorts per tile)
    const unsigned short* kfb =
        Kf + ((size_t)g*32*8 + wk*4)*512 + (size_t)lane*8;
    const unsigned short* vfb =
        Vf + ((size_t)g*32*8 + wk*4)*512 + (size_t)lane*8;

    int njw = maskv ? (qt + 1) : QT_;
    if (maskv && wq == 0 && wk == 1) njw = qt;  // diagonal tile fully masked

    // 4 independent PV accumulators (summed in the epilogue)
    f32x16 o00 = {}, o01 = {}, o10 = {}, o11 = {};
    float lsum = 0.f;

    // ---- depth-2 prefetch: static ping-pong buffers (rule: no runtime idx)
    bf16x8 ka[4], va[4], kb[4], vb[4];
    if (njw > 0) {
        #pragma unroll
        for (int s = 0; s < 4; ++s) {
            ka[s] = *(const bf16x8*)(kfb + s*512);
            va[s] = *(const bf16x8*)(vfb + s*512);
        }
    }
    if (njw > 1) {
        #pragma unroll
        for (int s = 0; s < 4; ++s) {
            kb[s] = *(const bf16x8*)(kfb + 4096 + s*512);
            vb[s] = *(const bf16x8*)(vfb + 4096 + s*512);
        }
    }

#define AITER(J, KC, VC)                                                      \
  {                                                                           \
    f32x16 st0 = {}, st1 = {};       /* two parallel 2-deep QK chains */      \
    __builtin_amdgcn_s_setprio(1);                                            \
    st0 = __builtin_amdgcn_mfma_f32_32x32x16_bf16(KC[0], qf[0], st0, 0,0,0);  \
    st1 = __builtin_amdgcn_mfma_f32_32x32x16_bf16(KC[1], qf[1], st1, 0,0,0);  \
    st0 = __builtin_amdgcn_mfma_f32_32x32x16_bf16(KC[2], qf[2], st0, 0,0,0);  \
    st1 = __builtin_amdgcn_mfma_f32_32x32x16_bf16(KC[3], qf[3], st1, 0,0,0);  \
    __builtin_amdgcn_s_setprio(0);                                            \
    if ((J) + 2 < njw) {   /* reload just-consumed K buffer for j+2 */        \
      const unsigned short* kp_ = kfb + (size_t)((J)+2)*4096;                 \
      KC[0] = *(const bf16x8*)(kp_);                                          \
      KC[1] = *(const bf16x8*)(kp_ + 512);                                    \
      KC[2] = *(const bf16x8*)(kp_ + 1024);                                   \
      KC[3] = *(const bf16x8*)(kp_ + 1536);                                   \
    }                                                                         \
    f32x16 st = st0 + st1;                                                    \
    float e[16];                                                              \
    const bool diag_ = maskv && ((J) == qt) && (wk == wq);                    \
    if (diag_) {                                                              \
      _Pragma("unroll")                                                       \
      for (int r = 0; r < 16; ++r) {                                          \
        int kr_ = (r&3) + 8*(r>>2) + 4*hi;                                    \
        float ev_ = fast_exp2(st[r]);                                         \
        e[r] = (kr_ >= l31) ? 0.f : ev_;                                      \
        lsum += e[r];                                                         \
      }                                                                       \
    } else {                                                                  \
      _Pragma("unroll")                                                       \
      for (int r = 0; r < 16; ++r) { e[r] = fast_exp2(st[r]); lsum += e[r]; } \
    }                                                                         \
    uint32_t p01_ = cvt_pk_bf16(e[0], e[1]),  p23_ = cvt_pk_bf16(e[2], e[3]); \
    uint32_t p45_ = cvt_pk_bf16(e[4], e[5]),  p67_ = cvt_pk_bf16(e[6], e[7]); \
    permlane32_swap(p01_, p45_); permlane32_swap(p23_, p67_);                 \
    uint32_t r01_ = cvt_pk_bf16(e[8], e[9]),  r23_ = cvt_pk_bf16(e[10], e[11]); \
    uint32_t r45_ = cvt_pk_bf16(e[12], e[13]), r67_ = cvt_pk_bf16(e[14], e[15]); \
    permlane32_swap(r01_, r45_); permlane32_swap(r23_, r67_);                 \
    union { uint32_t u[4]; bf16x8 v; } A0_, A1_;                              \
    A0_.u[0]=p01_; A0_.u[1]=p23_; A0_.u[2]=p45_; A0_.u[3]=p67_;               \
    A1_.u[0]=r01_; A1_.u[1]=r23_; A1_.u[2]=r45_; A1_.u[3]=r67_;               \
    __builtin_amdgcn_s_setprio(1);   /* 4 INDEPENDENT PV MFMAs */             \
    o00 = __builtin_amdgcn_mfma_f32_32x32x16_bf16(A0_.v, VC[0], o00, 0,0,0);  \
    o10 = __builtin_amdgcn_mfma_f32_32x32x16_bf16(A0_.v, VC[1], o10, 0,0,0);  \
    o01 = __builtin_amdgcn_mfma_f32_32x32x16_bf16(A1_.v, VC[2], o01, 0,0,0);  \
    o11 = __builtin_amdgcn_mfma_f32_32x32x16_bf16(A1_.v, VC[3], o11, 0,0,0);  \
    __builtin_amdgcn_s_setprio(0);                                            \
    if ((J) + 2 < njw) {   /* reload just-consumed V buffer for j+2 */        \
      const unsigned short* vp_ = vfb + (size_t)((J)+2)*4096;                 \
      VC[0] = *(const bf16x8*)(vp_);                                          \
      VC[1] = *(const bf16x8*)(vp_ + 512);                                    \
      VC[2] = *(const bf16x8*)(vp_ + 1024);                                   \
      VC[3] = *(const bf16x8*)(vp_ + 1536);                                   \
    }                                                                         \
  }

    int j = 0;
    for (; j + 1 < njw; j += 2) {
        AITER(j, ka, va);
        AITER(j+1, kb, vb);
    }
    if (j < njw) AITER(j, ka, va);
#undef AITER

    f32x16 o0 = o00 + o01;     // combine split PV accumulators
    f32x16 o1 = o10 + o11;

    // ---- cross-wk reduction + epilogue (one barrier) ----
    lsum += __shfl_xor(lsum, 32);   // combine hi/lo key quads: l for q=l31

    if (wk == 1) {
        #pragma unroll
        for (int r = 0; r < 16; ++r) {
            int qr = (r&3) + 8*(r>>2) + 4*hi;
            sm.red.osum[wq][qr][l31]      = o0[r];
            sm.red.osum[wq][qr][32 + l31] = o1[r];
        }
        if (hi == 0) sm.red.lsum[wq][l31] = lsum;
    }
    __syncthreads();
    if (wk == 0) {
        float inv = 1.0f / (lsum + sm.red.lsum[wq][l31]);   // inv for q = l31
        #pragma unroll
        for (int r = 0; r < 16; ++r) {
            int qr = (r&3) + 8*(r>>2) + 4*hi;
            float o0v = o0[r] + sm.red.osum[wq][qr][l31];
            float o1v = o1[r] + sm.red.osum[wq][qr][32 + l31];
            float invr = __shfl(inv, qr);
            int q = qt*64 + wq*32 + qr;
            if (!(maskv && q == 0)) {   // row 0 = mean(V), done above
                size_t base = ((size_t)(b*S_ + q))*D_ + h*64;
                ctx[base + l31]      = f2bf(o0v * invr);
                ctx[base + 32 + l31] = f2bf(o1v * invr);
            }
        }
    }
}

// ---------------------------------------------------------------------------
// Kernel 3: out = ctx @ Wo^T + bias   (M=4096, N=1024, K=1024, bf16 MFMA)
// 64x128 tile, 4 waves (each 64x32), BK=64, double-buffered, 1 barrier/kt.
// Grid (8, 64) = 512 blocks -> 2 blocks/CU; bid%8 = nt0 -> each XCD caches
// exactly one 128-col Wo panel (0.25 MB).
// ---------------------------------------------------------------------------
__global__ __launch_bounds__(256, 2) void proj_kernel(
    const unsigned short* __restrict__ A,    // ctx bf16 [4096][1024]
    const unsigned short* __restrict__ Bw,   // Wo bf16  [1024][1024]
    const float* __restrict__ bias,
    float* __restrict__ out)
{
    __shared__ unsigned short As[2][64][72];
    __shared__ unsigned short Bs[2][128][72];
    const int nt0 = blockIdx.x;   // 0..7   (N panel)
    const int mt0 = blockIdx.y;   // 0..63  (M panel)
    const int tid  = threadIdx.x;
    const int wave = tid >> 6, lane = tid & 63;
    const int quad = lane >> 4, ln = lane & 15;

    const int arow = tid >> 2, acol = (tid & 3)*16;   // A: 64 rows x 64 cols
    const int brow = tid >> 1, bcol = (tid & 1)*32;   // B: 128 rows x 64 cols
    const unsigned short* aptr = A  + ((size_t)(mt0*64  + arow)*1024 + acol);
    const unsigned short* bptr = Bw + ((size_t)(nt0*128 + brow)*1024 + bcol);

    uint4 a0 = ((const uint4*)aptr)[0], a1 = ((const uint4*)aptr)[1];
    uint4 b0 = ((const uint4*)bptr)[0], b1 = ((const uint4*)bptr)[1],
          b2 = ((const uint4*)bptr)[2], b3 = ((const uint4*)bptr)[3];

    f32x4 acc[4][2] = {};

    for (int kt = 0; kt < 16; ++kt) {
        const int cur = kt & 1;
        *((uint4*)&As[cur][arow][acol])    = a0;
        *((uint4*)&As[cur][arow][acol+8])  = a1;
        *((uint4*)&Bs[cur][brow][bcol])    = b0;
        *((uint4*)&Bs[cur][brow][bcol+8])  = b1;
        *((uint4*)&Bs[cur][brow][bcol+16]) = b2;
        *((uint4*)&Bs[cur][brow][bcol+24]) = b3;
        uint4 na0, na1, nb0, nb1, nb2, nb3;
        if (kt < 15) {
            const unsigned short* ap = aptr + (kt+1)*64;
            const unsigned short* bp = bptr + (kt+1)*64;
            na0 = ((const uint4*)ap)[0]; na1 = ((const uint4*)ap)[1];
            nb0 = ((const uint4*)bp)[0]; nb1 = ((const uint4*)bp)[1];
            nb2 = ((const uint4*)bp)[2]; nb3 = ((const uint4*)bp)[3];
        }
        __syncthreads();
        #pragma unroll
        for (int ks = 0; ks < 2; ++ks) {
            bf16x8 am[4], bn[2];
            #pragma unroll
            for (int i = 0; i < 4; ++i)
                am[i] = *(const bf16x8*)&As[cur][i*16 + ln][ks*32 + quad*8];
            #pragma unroll
            for (int i = 0; i < 2; ++i)
                bn[i] = *(const bf16x8*)&Bs[cur][wave*32 + i*16 + ln][ks*32 + quad*8];
            #pragma unroll
            for (int mi = 0; mi < 4; ++mi)
                #pragma unroll
                for (int ni = 0; ni < 2; ++ni)
                    acc[mi][ni] = __builtin_amdgcn_mfma_f32_16x16x32_bf16(
                        am[mi], bn[ni], acc[mi][ni], 0,0,0);
        }
        a0 = na0; a1 = na1;
        b0 = nb0; b1 = nb1; b2 = nb2; b3 = nb3;
    }

    #pragma unroll
    for (int mi = 0; mi < 4; ++mi)
        #pragma unroll
        for (int ni = 0; ni < 2; ++ni) {
            int row = mt0*64 + mi*16 + quad*4;
            int col = nt0*128 + wave*32 + ni*16 + ln;
            float bv = bias[col];
            #pragma unroll
            for (int r = 0; r < 4; ++r)
                out[(size_t)(row + r)*1024 + col] = acc[mi][ni][r] + bv;
        }
}

// ---------------------------------------------------------------------------
extern "C" void kernel_launch(void* const* d_in, const int* in_sizes, int n_in,
                              void* d_out, int out_size, void* d_ws, size_t ws_size,
                              hipStream_t stream)
{
    const float* Q   = (const float*)d_in[0];
    const float* K   = (const float*)d_in[1];
    const float* V   = (const float*)d_in[2];
    const float* Wo  = (const float*)d_in[3];
    const float* Wb  = (const float*)d_in[4];
    const int* maskp = (const int*)d_in[5];
    float* out = (float*)d_out;

    // workspace layout (ushort units)
    unsigned short* Kf   = (unsigned short*)d_ws;              // 8.39 MB
    unsigned short* Vf   = Kf  + (size_t)B_*S_*D_;             // 8.39 MB
    unsigned short* Wob  = Vf  + (size_t)B_*S_*D_;             // 2.10 MB
    unsigned short* ctxb = Wob + (size_t)D_*D_;                // 8.39 MB
    float* Pv = (float*)(ctxb + (size_t)B_*S_*D_);             // 0.26 MB

    prep_kernel<<<3072, 256, 0, stream>>>(K, V, Wo, Kf, Vf, Wob, Pv);
    attn_kernel<<<1024, 256, 0, stream>>>(Q, Kf, Vf, Pv, ctxb, maskp);
    proj_kernel<<<dim3(8, 64), 256, 0, stream>>>(ctxb, Wob, Wb, out);
}

// Round 9
// 143.367 us; speedup vs baseline: 1.0046x; 1.0046x over previous
//
#include <hip/hip_runtime.h>
#include <hip/hip_bf16.h>
#include <stdint.h>

// Problem constants
#define B_  2
#define S_  2048
#define D_  1024
#define H_  16
#define DQ_ 64
#define QT_ (S_/64)   // 32 q-tiles (64 rows each) per (b,h)

// softmax is shift-invariant -> no max subtraction needed at all.
// scale folded into Q pack: qb = bf16(q * 0.125 * log2(e)), P = exp2(K·qb)
#define C1_ 0.18033688011112042f   // 0.125 * log2(e)

typedef float f32x4  __attribute__((ext_vector_type(4)));
typedef float f32x16 __attribute__((ext_vector_type(16)));
typedef short bf16x8 __attribute__((ext_vector_type(8)));

__device__ __forceinline__ unsigned short f2bf(float f) {
    uint32_t u = __float_as_uint(f);
    u += 0x7fffu + ((u >> 16) & 1u);   // round-to-nearest-even
    return (unsigned short)(u >> 16);
}
__device__ __forceinline__ float bf2f(unsigned short u) {
    return __uint_as_float(((uint32_t)u) << 16);
}
__device__ __forceinline__ float fast_exp2(float x) {
#if __has_builtin(__builtin_amdgcn_exp2f)
    return __builtin_amdgcn_exp2f(x);
#else
    float r; asm("v_exp_f32 %0, %1" : "=v"(r) : "v"(x)); return r;
#endif
}
__device__ __forceinline__ uint32_t cvt_pk_bf16(float lo, float hi) {
    uint32_t r;
    asm("v_cvt_pk_bf16_f32 %0, %1, %2" : "=v"(r) : "v"(lo), "v"(hi));
    return r;
}
// vdst[32..63] <-> vsrc[0..31]
__device__ __forceinline__ void permlane32_swap(uint32_t &a, uint32_t &b) {
    asm volatile("v_permlane32_swap_b32 %0, %1" : "+v"(a), "+v"(b));
}

// ---------------------------------------------------------------------------
// Kernel 1: prep. Emits K and V in EXACT 32x32x16-MFMA fragment order via an
// LDS-staged tile transpose so BOTH the global loads (row-segmented float4,
// 16 cache lines / wave-instr) and the fragment stores (consecutive tid ->
// consecutive 16B) are fully coalesced. Also Wo fp32->bf16 and Pv column
// partials (row-0 mean(V)). Grid 3072 x 256:
//   [0,1024)    : Vf fragments + Pv   (g = blk>>5, j = blk&31)
//   [1024,2048) : Kf fragments
//   [2048,3072) : Wo convert
// Kf frag fb = wk*4+s : lane l holds K[j*64+wk*32+(l&31)][s*16+(l>>5)*8 + 0..7]
// Vf frag fb = s*2+kk : lane l holds V[j*64+s*16+(l>>5)*8 + 0..7][kk*32+(l&31)]
// ---------------------------------------------------------------------------
__global__ __launch_bounds__(256) void prep_kernel(
    const float* __restrict__ K, const float* __restrict__ V,
    const float* __restrict__ W,
    unsigned short* __restrict__ Kf, unsigned short* __restrict__ Vf,
    unsigned short* __restrict__ Wb, float* __restrict__ Pv)
{
    __shared__ unsigned short Ls[64][72];
    __shared__ float Pp[8][64];
    const int blk = blockIdx.x, tid = threadIdx.x;

    if (blk < 2048) {
        const bool isV = blk < 1024;
        const int gb = isV ? blk : (blk - 1024);
        const int g = gb >> 5, j = gb & 31;
        const int b = g >> 4, h = g & 15;
        const float* src0 = (isV ? V : K) + ((size_t)(b*S_ + j*64))*D_ + h*64;

        // phase A: coalesced tile load (64 rows x 64 cols fp32) -> bf16 LDS
        {
            int row = tid >> 2, col0 = (tid & 3) * 16;
            const float* src = src0 + (size_t)row*D_ + col0;
            float4 f0 = ((const float4*)src)[0];
            float4 f1 = ((const float4*)src)[1];
            float4 f2 = ((const float4*)src)[2];
            float4 f3 = ((const float4*)src)[3];
            unsigned short* d = &Ls[row][col0];
            d[0]=f2bf(f0.x); d[1]=f2bf(f0.y); d[2]=f2bf(f0.z); d[3]=f2bf(f0.w);
            d[4]=f2bf(f1.x); d[5]=f2bf(f1.y); d[6]=f2bf(f1.z); d[7]=f2bf(f1.w);
            d[8]=f2bf(f2.x); d[9]=f2bf(f2.y); d[10]=f2bf(f2.z); d[11]=f2bf(f2.w);
            d[12]=f2bf(f3.x); d[13]=f2bf(f3.y); d[14]=f2bf(f3.z); d[15]=f2bf(f3.w);
        }
        __syncthreads();

        if (isV) {
            // phase B: transpose via LDS scalar reads -> coalesced frag stores
            #pragma unroll
            for (int ps = 0; ps < 2; ++ps) {
                const int slot = tid + ps*256;
                const int fb = slot >> 6, l = slot & 63;
                const int s = fb >> 1, kk = fb & 1;
                const int hi = l >> 5, l31 = l & 31;
                const int dcol = kk*32 + l31;
                unsigned short us[8];
                float p = 0.f;
                #pragma unroll
                for (int r = 0; r < 8; ++r) {
                    unsigned short u = Ls[s*16 + hi*8 + r][dcol];
                    us[r] = u;
                    p += bf2f(u);
                }
                *(uint4*)(Vf + ((size_t)gb*8 + fb)*512 + (size_t)l*8) = *(uint4*)us;
                Pp[s*2 + hi][dcol] = p;
            }
            __syncthreads();
            if (tid < 64) {
                float t = 0.f;
                #pragma unroll
                for (int i = 0; i < 8; ++i) t += Pp[i][tid];
                Pv[((size_t)g*64 + tid)*32 + j] = t;
            }
        } else {
            // phase B: rows are fragment-contiguous -> b128 LDS reads
            #pragma unroll
            for (int ps = 0; ps < 2; ++ps) {
                const int slot = tid + ps*256;
                const int fb = slot >> 6, l = slot & 63;
                const int wk = fb >> 2, s = fb & 3;
                const int hi = l >> 5, l31 = l & 31;
                uint4 val = *(const uint4*)&Ls[wk*32 + l31][s*16 + hi*8];
                *(uint4*)(Kf + ((size_t)gb*8 + fb)*512 + (size_t)l*8) = val;
            }
        }
    } else {
        int i = (blk - 2048)*256 + tid;     // < D*D/4 = 262144
        float4 f = ((const float4*)W)[i];
        ushort4 o;
        o.x = f2bf(f.x); o.y = f2bf(f.y); o.z = f2bf(f.z); o.w = f2bf(f.w);
        ((ushort4*)Wb)[i] = o;
    }
}

// ---------------------------------------------------------------------------
// Kernel 2: flash attention, 32x32x16 MFMA, zero-LDS main loop.
// R9 change: DEPTH-3 prefetch (unroll-3 rotation ka/kb/kc, va/vb/vc).
// Rationale: per-XCD Kf/Vf working set (~4MB) == L2 capacity, so a fraction
// of fragment loads miss to L3 (~500-900cy). Depth-2 gave only ~1 iteration
// (~500cy) of slack; depth-3 issues loads 2 full iterations (~1000cy) ahead.
// R6 proved wave-count is not the lever (cache-latency-bound), so the VGPR
// cost (+32, possibly 2 blocks/CU) is acceptable.
// Retained from R8: two parallel QK chains (st0/st1), 4 independent PV
// accumulators, longest-first balanced qt map, Q staged via LDS, setprio,
// shift-free softmax, per-wave causal niter, bid&7 XCD affinity, 1 barrier.
// launch_bounds (256,2): do NOT raise the 2nd arg (R4/R5: allocator spill).
// Spill tripwire: attn WRITE_SIZE must stay ~8.2MB.
// ---------------------------------------------------------------------------
__global__ __launch_bounds__(256, 2) void attn_kernel(
    const float* __restrict__ Q,
    const unsigned short* __restrict__ Kf,
    const unsigned short* __restrict__ Vf,
    const float* __restrict__ Pv,
    unsigned short* __restrict__ ctx,
    const int* __restrict__ maskp)
{
    __shared__ union {
        unsigned short qs[64][72];                    // Q staging (prologue)
        struct { float osum[2][32][68]; float lsum[2][32]; } red;  // epilogue
    } sm;

    const int bid = blockIdx.x;
    const int g = bid & 31;             // h + 16*b ; g&7 = bid&7 -> XCD
    const int p = bid >> 5;             // [0,32)
    // longest-first balanced permutation: octiles -> qt {31..24,16..23,15..8,0..7}
    const int qt = (p < 8) ? 31 - p : (p < 16) ? p + 8 : (p < 24) ? 31 - p : p - 24;
    const int h = g & 15, b = g >> 4;
    const int tid  = threadIdx.x;
    const int wave = tid >> 6, lane = tid & 63;
    const int wq = wave >> 1, wk = wave & 1;
    const int hi = lane >> 5, l31 = lane & 31;
    const int maskv = maskp[0];

    // fused mean(V) -> ctx row 0, cols [h*64, h*64+64)
    if (maskv && qt == 0 && tid < 64) {
        const float* pv = Pv + ((size_t)g*64 + tid)*32;
        float s = 0.f;
        #pragma unroll
        for (int i = 0; i < 32; ++i) s += pv[i];
        ctx[(size_t)b*S_*D_ + h*64 + tid] = f2bf(s * (1.0f/S_));
    }

    // ---- stage Q tile (coalesced) -> LDS as pre-scaled bf16 ----
    {
        const int row = tid >> 2, col0 = (tid & 3) * 16;
        const float* src = Q + ((size_t)(b*S_ + qt*64 + row))*D_ + h*64 + col0;
        float4 f0 = ((const float4*)src)[0];
        float4 f1 = ((const float4*)src)[1];
        float4 f2 = ((const float4*)src)[2];
        float4 f3 = ((const float4*)src)[3];
        unsigned short* d = &sm.qs[row][col0];
        d[0]=f2bf(f0.x*C1_); d[1]=f2bf(f0.y*C1_); d[2]=f2bf(f0.z*C1_); d[3]=f2bf(f0.w*C1_);
        d[4]=f2bf(f1.x*C1_); d[5]=f2bf(f1.y*C1_); d[6]=f2bf(f1.z*C1_); d[7]=f2bf(f1.w*C1_);
        d[8]=f2bf(f2.x*C1_); d[9]=f2bf(f2.y*C1_); d[10]=f2bf(f2.z*C1_); d[11]=f2bf(f2.w*C1_);
        d[12]=f2bf(f3.x*C1_); d[13]=f2bf(f3.y*C1_); d[14]=f2bf(f3.z*C1_); d[15]=f2bf(f3.w*C1_);
    }
    __syncthreads();
    bf16x8 qf[4];
    #pragma unroll
    for (int s = 0; s < 4; ++s)
        qf[s] = *(const bf16x8*)&sm.qs[wq*32 + l31][s*16 + hi*8];
    __syncthreads();   // Qs reads done before epilogue aliases the buffer

    // fragment bases (advance by j*4096 ushorts per tile)
    const unsigned short* kfb =
        Kf + ((size_t)g*32*8 + wk*4)*512 + (size_t)lane*8;
    const unsigned short* vfb =
        Vf + ((size_t)g*32*8 + wk*4)*512 + (size_t)lane*8;

    int njw = maskv ? (qt + 1) : QT_;
    if (maskv && wq == 0 && wk == 1) njw = qt;  // diagonal tile fully masked

    // 4 independent PV accumulators (summed in the epilogue)
    f32x16 o00 = {}, o01 = {}, o10 = {}, o11 = {};
    float lsum = 0.f;

    // ---- depth-3 prefetch: static 3-buffer rotation (no runtime idx)
    bf16x8 ka[4], va[4], kb[4], vb[4], kc3[4], vc3[4];
    if (njw > 0) {
        #pragma unroll
        for (int s = 0; s < 4; ++s) {
            ka[s] = *(const bf16x8*)(kfb + s*512);
            va[s] = *(const bf16x8*)(vfb + s*512);
        }
    }
    if (njw > 1) {
        #pragma unroll
        for (int s = 0; s < 4; ++s) {
            kb[s] = *(const bf16x8*)(kfb + 4096 + s*512);
            vb[s] = *(const bf16x8*)(vfb + 4096 + s*512);
        }
    }
    if (njw > 2) {
        #pragma unroll
        for (int s = 0; s < 4; ++s) {
            kc3[s] = *(const bf16x8*)(kfb + 8192 + s*512);
            vc3[s] = *(const bf16x8*)(vfb + 8192 + s*512);
        }
    }

#define AITER(J, KC, VC)                                                      \
  {                                                                           \
    f32x16 st0 = {}, st1 = {};       /* two parallel 2-deep QK chains */      \
    __builtin_amdgcn_s_setprio(1);                                            \
    st0 = __builtin_amdgcn_mfma_f32_32x32x16_bf16(KC[0], qf[0], st0, 0,0,0);  \
    st1 = __builtin_amdgcn_mfma_f32_32x32x16_bf16(KC[1], qf[1], st1, 0,0,0);  \
    st0 = __builtin_amdgcn_mfma_f32_32x32x16_bf16(KC[2], qf[2], st0, 0,0,0);  \
    st1 = __builtin_amdgcn_mfma_f32_32x32x16_bf16(KC[3], qf[3], st1, 0,0,0);  \
    __builtin_amdgcn_s_setprio(0);                                            \
    if ((J) + 3 < njw) {   /* reload just-consumed K buffer for j+3 */        \
      const unsigned short* kp_ = kfb + (size_t)((J)+3)*4096;                 \
      KC[0] = *(const bf16x8*)(kp_);                                          \
      KC[1] = *(const bf16x8*)(kp_ + 512);                                    \
      KC[2] = *(const bf16x8*)(kp_ + 1024);                                   \
      KC[3] = *(const bf16x8*)(kp_ + 1536);                                   \
    }                                                                         \
    f32x16 st = st0 + st1;                                                    \
    float e[16];                                                              \
    const bool diag_ = maskv && ((J) == qt) && (wk == wq);                    \
    if (diag_) {                                                              \
      _Pragma("unroll")                                                       \
      for (int r = 0; r < 16; ++r) {                                          \
        int kr_ = (r&3) + 8*(r>>2) + 4*hi;                                    \
        float ev_ = fast_exp2(st[r]);                                         \
        e[r] = (kr_ >= l31) ? 0.f : ev_;                                      \
        lsum += e[r];                                                         \
      }                                                                       \
    } else {                                                                  \
      _Pragma("unroll")                                                       \
      for (int r = 0; r < 16; ++r) { e[r] = fast_exp2(st[r]); lsum += e[r]; } \
    }                                                                         \
    uint32_t p01_ = cvt_pk_bf16(e[0], e[1]),  p23_ = cvt_pk_bf16(e[2], e[3]); \
    uint32_t p45_ = cvt_pk_bf16(e[4], e[5]),  p67_ = cvt_pk_bf16(e[6], e[7]); \
    permlane32_swap(p01_, p45_); permlane32_swap(p23_, p67_);                 \
    uint32_t r01_ = cvt_pk_bf16(e[8], e[9]),  r23_ = cvt_pk_bf16(e[10], e[11]); \
    uint32_t r45_ = cvt_pk_bf16(e[12], e[13]), r67_ = cvt_pk_bf16(e[14], e[15]); \
    permlane32_swap(r01_, r45_); permlane32_swap(r23_, r67_);                 \
    union { uint32_t u[4]; bf16x8 v; } A0_, A1_;                              \
    A0_.u[0]=p01_; A0_.u[1]=p23_; A0_.u[2]=p45_; A0_.u[3]=p67_;               \
    A1_.u[0]=r01_; A1_.u[1]=r23_; A1_.u[2]=r45_; A1_.u[3]=r67_;               \
    __builtin_amdgcn_s_setprio(1);   /* 4 INDEPENDENT PV MFMAs */             \
    o00 = __builtin_amdgcn_mfma_f32_32x32x16_bf16(A0_.v, VC[0], o00, 0,0,0);  \
    o10 = __builtin_amdgcn_mfma_f32_32x32x16_bf16(A0_.v, VC[1], o10, 0,0,0);  \
    o01 = __builtin_amdgcn_mfma_f32_32x32x16_bf16(A1_.v, VC[2], o01, 0,0,0);  \
    o11 = __builtin_amdgcn_mfma_f32_32x32x16_bf16(A1_.v, VC[3], o11, 0,0,0);  \
    __builtin_amdgcn_s_setprio(0);                                            \
    if ((J) + 3 < njw) {   /* reload just-consumed V buffer for j+3 */        \
      const unsigned short* vp_ = vfb + (size_t)((J)+3)*4096;                 \
      VC[0] = *(const bf16x8*)(vp_);                                          \
      VC[1] = *(const bf16x8*)(vp_ + 512);                                    \
      VC[2] = *(const bf16x8*)(vp_ + 1024);                                   \
      VC[3] = *(const bf16x8*)(vp_ + 1536);                                   \
    }                                                                         \
  }

    int j = 0;
    for (; j + 2 < njw; j += 3) {
        AITER(j,   ka,  va);
        AITER(j+1, kb,  vb);
        AITER(j+2, kc3, vc3);
    }
    if (j < njw)     AITER(j,   ka, va);
    if (j+1 < njw)   AITER(j+1, kb, vb);
#undef AITER

    f32x16 o0 = o00 + o01;     // combine split PV accumulators
    f32x16 o1 = o10 + o11;

    // ---- cross-wk reduction + epilogue (one barrier) ----
    lsum += __shfl_xor(lsum, 32);   // combine hi/lo key quads: l for q=l31

    if (wk == 1) {
        #pragma unroll
        for (int r = 0; r < 16; ++r) {
            int qr = (r&3) + 8*(r>>2) + 4*hi;
            sm.red.osum[wq][qr][l31]      = o0[r];
            sm.red.osum[wq][qr][32 + l31] = o1[r];
        }
        if (hi == 0) sm.red.lsum[wq][l31] = lsum;
    }
    __syncthreads();
    if (wk == 0) {
        float inv = 1.0f / (lsum + sm.red.lsum[wq][l31]);   // inv for q = l31
        #pragma unroll
        for (int r = 0; r < 16; ++r) {
            int qr = (r&3) + 8*(r>>2) + 4*hi;
            float o0v = o0[r] + sm.red.osum[wq][qr][l31];
            float o1v = o1[r] + sm.red.osum[wq][qr][32 + l31];
            float invr = __shfl(inv, qr);
            int q = qt*64 + wq*32 + qr;
            if (!(maskv && q == 0)) {   // row 0 = mean(V), done above
                size_t base = ((size_t)(b*S_ + q))*D_ + h*64;
                ctx[base + l31]      = f2bf(o0v * invr);
                ctx[base + 32 + l31] = f2bf(o1v * invr);
            }
        }
    }
}

// ---------------------------------------------------------------------------
// Kernel 3: out = ctx @ Wo^T + bias   (M=4096, N=1024, K=1024, bf16 MFMA)
// 64x128 tile, 4 waves (each 64x32), BK=64, double-buffered, 1 barrier/kt.
// Grid (8, 64) = 512 blocks -> 2 blocks/CU; bid%8 = nt0 -> each XCD caches
// exactly one 128-col Wo panel (0.25 MB).
// ---------------------------------------------------------------------------
__global__ __launch_bounds__(256, 2) void proj_kernel(
    const unsigned short* __restrict__ A,    // ctx bf16 [4096][1024]
    const unsigned short* __restrict__ Bw,   // Wo bf16  [1024][1024]
    const float* __restrict__ bias,
    float* __restrict__ out)
{
    __shared__ unsigned short As[2][64][72];
    __shared__ unsigned short Bs[2][128][72];
    const int nt0 = blockIdx.x;   // 0..7   (N panel)
    const int mt0 = blockIdx.y;   // 0..63  (M panel)
    const int tid  = threadIdx.x;
    const int wave = tid >> 6, lane = tid & 63;
    const int quad = lane >> 4, ln = lane & 15;

    const int arow = tid >> 2, acol = (tid & 3)*16;   // A: 64 rows x 64 cols
    const int brow = tid >> 1, bcol = (tid & 1)*32;   // B: 128 rows x 64 cols
    const unsigned short* aptr = A  + ((size_t)(mt0*64  + arow)*1024 + acol);
    const unsigned short* bptr = Bw + ((size_t)(nt0*128 + brow)*1024 + bcol);

    uint4 a0 = ((const uint4*)aptr)[0], a1 = ((const uint4*)aptr)[1];
    uint4 b0 = ((const uint4*)bptr)[0], b1 = ((const uint4*)bptr)[1],
          b2 = ((const uint4*)bptr)[2], b3 = ((const uint4*)bptr)[3];

    f32x4 acc[4][2] = {};

    for (int kt = 0; kt < 16; ++kt) {
        const int cur = kt & 1;
        *((uint4*)&As[cur][arow][acol])    = a0;
        *((uint4*)&As[cur][arow][acol+8])  = a1;
        *((uint4*)&Bs[cur][brow][bcol])    = b0;
        *((uint4*)&Bs[cur][brow][bcol+8])  = b1;
        *((uint4*)&Bs[cur][brow][bcol+16]) = b2;
        *((uint4*)&Bs[cur][brow][bcol+24]) = b3;
        uint4 na0, na1, nb0, nb1, nb2, nb3;
        if (kt < 15) {
            const unsigned short* ap = aptr + (kt+1)*64;
            const unsigned short* bp = bptr + (kt+1)*64;
            na0 = ((const uint4*)ap)[0]; na1 = ((const uint4*)ap)[1];
            nb0 = ((const uint4*)bp)[0]; nb1 = ((const uint4*)bp)[1];
            nb2 = ((const uint4*)bp)[2]; nb3 = ((const uint4*)bp)[3];
        }
        __syncthreads();
        #pragma unroll
        for (int ks = 0; ks < 2; ++ks) {
            bf16x8 am[4], bn[2];
            #pragma unroll
            for (int i = 0; i < 4; ++i)
                am[i] = *(const bf16x8*)&As[cur][i*16 + ln][ks*32 + quad*8];
            #pragma unroll
            for (int i = 0; i < 2; ++i)
                bn[i] = *(const bf16x8*)&Bs[cur][wave*32 + i*16 + ln][ks*32 + quad*8];
            #pragma unroll
            for (int mi = 0; mi < 4; ++mi)
                #pragma unroll
                for (int ni = 0; ni < 2; ++ni)
                    acc[mi][ni] = __builtin_amdgcn_mfma_f32_16x16x32_bf16(
                        am[mi], bn[ni], acc[mi][ni], 0,0,0);
        }
        a0 = na0; a1 = na1;
        b0 = nb0; b1 = nb1; b2 = nb2; b3 = nb3;
    }

    #pragma unroll
    for (int mi = 0; mi < 4; ++mi)
        #pragma unroll
        for (int ni = 0; ni < 2; ++ni) {
            int row = mt0*64 + mi*16 + quad*4;
            int col = nt0*128 + wave*32 + ni*16 + ln;
            float bv = bias[col];
            #pragma unroll
            for (int r = 0; r < 4; ++r)
                out[(size_t)(row + r)*1024 + col] = acc[mi][ni][r] + bv;
        }
}

// ---------------------------------------------------------------------------
extern "C" void kernel_launch(void* const* d_in, const int* in_sizes, int n_in,
                              void* d_out, int out_size, void* d_ws, size_t ws_size,
                              hipStream_t stream)
{
    const float* Q   = (const float*)d_in[0];
    const float* K   = (const float*)d_in[1];
    const float* V   = (const float*)d_in[2];
    const float* Wo  = (const float*)d_in[3];
    const float* Wb  = (const float*)d_in[4];
    const int* maskp = (const int*)d_in[5];
    float* out = (float*)d_out;

    // workspace layout (ushort units)
    unsigned short* Kf   = (unsigned short*)d_ws;              // 8.39 MB
    unsigned short* Vf   = Kf  + (size_t)B_*S_*D_;             // 8.39 MB
    unsigned short* Wob  = Vf  + (size_t)B_*S_*D_;             // 2.10 MB
    unsigned short* ctxb = Wob + (size_t)D_*D_;                // 8.39 MB
    float* Pv = (float*)(ctxb + (size_t)B_*S_*D_);             // 0.26 MB

    prep_kernel<<<3072, 256, 0, stream>>>(K, V, Wo, Kf, Vf, Wob, Pv);
    attn_kernel<<<1024, 256, 0, stream>>>(Q, Kf, Vf, Pv, ctxb, maskp);
    proj_kernel<<<dim3(8, 64), 256, 0, stream>>>(ctxb, Wob, Wb, out);
}